// Round 8
// baseline (50.852 us; speedup 1.0000x reference)
//
#include <hip/hip_runtime.h>

// Shapley fusion — DIAGNOSTIC ROUND 2 (r8): r7's kernel body looped 8x,
// idempotently. Purpose: push the dispatch to ~50-57us so it beats the
// harness's 40us fill kernels into the rocprof top-5, exposing for the
// first time: device Start/End duration (vs bench wall -> isolates the
// suspected ~9.7us graph-replay overhead), FETCH_SIZE (is feats L3-resident
// on replays?), VALUBusy (is the 5.95us hot pass VALU-bound?), VGPR_Count.
// Decision rule in the round notes.
//
// f(subset) = relu(b + sum_{l in subset} d[l]), d[l] = dot(feats[l,:,n], w);
// Shapley coef for L=5 by subset size: {-, -0.6, 0.05, 1/30, 0.05, 0.2}.

constexpr int L_VIEWS = 5;
constexpr int C_CH    = 64;
constexpr int NPIX    = 128 * 256;   // 32768
constexpr int REPEATS = 8;           // diagnostic loop count

typedef float floatx4 __attribute__((ext_vector_type(4)));

__global__ __launch_bounds__(256, 4)
void shapley_fusion_kernel(const float* __restrict__ feats,
                           const float* __restrict__ w,
                           const float* __restrict__ bptr,
                           float* __restrict__ out)
{
    const int tid  = threadIdx.x;
    const int h    = tid >> 6;         // wave in block (0..3): channel quarter
    const int lane = tid & 63;
    const int q    = lane & 7;         // n-quad within the 32-n window
    const int g    = (lane >> 3) & 7;  // channel group within wave
    const int win  = blockIdx.x * 32;  // 128-B aligned n window
    const int nq   = win + q * 4;
    const int cA   = h * 8 + g;        // this thread's 2 channels
    const int cB   = cA + 32;

    const float w0   = w[cA];
    const float w1   = w[cB];
    const float bias = bptr[0];

    __shared__ float4 xl[4][8][L_VIEWS];      // [wave][quad][l] = d[l][0..3]

    for (int it = 0; it < REPEATS; ++it) {
        // Force real reloads each pass (no register-caching across iters).
        asm volatile("" ::: "memory");

        // ---- Phase A: load 10 float4s; 8 rows x 128-B full lines per inst.
        float4 va[L_VIEWS][2];
#pragma unroll
        for (int l = 0; l < L_VIEWS; ++l) {
            va[l][0] = *reinterpret_cast<const float4*>(
                feats + ((size_t)(l * C_CH + cA) * NPIX + nq));
            va[l][1] = *reinterpret_cast<const float4*>(
                feats + ((size_t)(l * C_CH + cB) * NPIX + nq));
        }

        float d[L_VIEWS][4];
#pragma unroll
        for (int l = 0; l < L_VIEWS; ++l) {
            d[l][0] = va[l][0].x * w0 + va[l][1].x * w1;
            d[l][1] = va[l][0].y * w0 + va[l][1].y * w1;
            d[l][2] = va[l][0].z * w0 + va[l][1].z * w1;
            d[l][3] = va[l][0].w * w0 + va[l][1].w * w1;
        }

        // Butterfly over the 8 channel-groups (lane bits 3..5).
#pragma unroll
        for (int l = 0; l < L_VIEWS; ++l) {
#pragma unroll
            for (int j = 0; j < 4; ++j) {
                d[l][j] += __shfl_xor(d[l][j], 8, 64);
                d[l][j] += __shfl_xor(d[l][j], 16, 64);
                d[l][j] += __shfl_xor(d[l][j], 32, 64);
            }
        }

        // ---- Cross-wave exchange (2.5 KB LDS). ----
        if (it != 0) __syncthreads();   // protect xl reuse across iterations
        if (g == 0) {
#pragma unroll
            for (int l = 0; l < L_VIEWS; ++l) {
                float4 t; t.x = d[l][0]; t.y = d[l][1]; t.z = d[l][2]; t.w = d[l][3];
                xl[h][q][l] = t;
            }
        }
        __syncthreads();

        // Each thread finalizes d only for its own j = g&3.
        const int jm = g & 3;
        const float* xf = reinterpret_cast<const float*>(xl);
        float dm[L_VIEWS];
#pragma unroll
        for (int l = 0; l < L_VIEWS; ++l) {
            float s = 0.f;
#pragma unroll
            for (int hh = 0; hh < 4; ++hh)
                s += xf[(((hh * 8 + q) * L_VIEWS) + l) * 4 + jm];
            dm[l] = s;
        }

        // ---- Phase B: Gray-code subset walk -> shapley -> softmax.
        constexpr float WTS[6] = {0.f, -0.6f, 0.05f, 1.0f / 30.0f, 0.05f, 0.2f};
        float S = bias;
        float sh[L_VIEWS] = {0.f, 0.f, 0.f, 0.f, 0.f};
#pragma unroll
        for (int t = 1; t < 32; ++t) {
            const int gm   = t ^ (t >> 1);
            const int bit  = __builtin_ctz(t);
            const bool add = (gm >> bit) & 1;
            S = add ? (S + dm[bit]) : (S - dm[bit]);
            const float f  = fmaxf(S, 0.f);
            const float wt = WTS[__builtin_popcount(gm)];
#pragma unroll
            for (int i = 0; i < L_VIEWS; ++i)
                if (gm & (1 << i)) sh[i] += wt * f;
        }

        float mx = sh[0];
#pragma unroll
        for (int i = 1; i < L_VIEWS; ++i) mx = fmaxf(mx, sh[i]);
        float e[L_VIEWS];
        float sum = 0.f;
#pragma unroll
        for (int i = 0; i < L_VIEWS; ++i) { e[i] = __expf(sh[i] - mx); sum += e[i]; }
        const float inv = 1.f / sum;
        float attn_mine[L_VIEWS];
#pragma unroll
        for (int i = 0; i < L_VIEWS; ++i) attn_mine[i] = e[i] * inv;

        // Redistribute: attn[l][j] lives at lane q + 8*j.
        float attn[L_VIEWS][4];
#pragma unroll
        for (int l = 0; l < L_VIEWS; ++l)
#pragma unroll
            for (int j = 0; j < 4; ++j)
                attn[l][j] = __shfl(attn_mine[l], q + 8 * j, 64);

        // ---- Phase C: fused output straight from registers.
#pragma unroll
        for (int k = 0; k < 2; ++k) {
            const int c = (k == 0) ? cA : cB;
            floatx4 acc;
            acc.x = va[0][k].x * attn[0][0];
            acc.y = va[0][k].y * attn[0][1];
            acc.z = va[0][k].z * attn[0][2];
            acc.w = va[0][k].w * attn[0][3];
#pragma unroll
            for (int l = 1; l < L_VIEWS; ++l) {
                acc.x += va[l][k].x * attn[l][0];
                acc.y += va[l][k].y * attn[l][1];
                acc.z += va[l][k].z * attn[l][2];
                acc.w += va[l][k].w * attn[l][3];
            }
            __builtin_nontemporal_store(acc,
                reinterpret_cast<floatx4*>(out + (size_t)c * NPIX + nq));
        }
    }
}

extern "C" void kernel_launch(void* const* d_in, const int* in_sizes, int n_in,
                              void* d_out, int out_size, void* d_ws, size_t ws_size,
                              hipStream_t stream) {
    const float* feats = (const float*)d_in[0];   // [5,64,128,256] fp32
    const float* w     = (const float*)d_in[1];   // [64,1] fp32
    const float* b     = (const float*)d_in[2];   // [1] fp32
    float* out         = (float*)d_out;           // [64,128,256] fp32

    // 1024 blocks x 256 threads; block owns a 32-n (128 B) window.
    shapley_fusion_kernel<<<NPIX / 32, 256, 0, stream>>>(feats, w, b, out);
}

// Round 9
// 20.141 us; speedup vs baseline: 2.5248x; 2.5248x over previous
//
#include <hip/hip_runtime.h>

// Shapley fusion: L=5 views, C=64 channels, N=128*256 spatial positions.
// f(subset) = relu(b + sum_{l in subset} d[l]) where d[l] = dot(feats[l,:,n], w)
// -- the reference's [M,N,C] subset GEMM collapses to 5 dots per pixel.
// Shapley coef for L=5 by subset size: {-, -0.6, 0.05, 1/30, 0.05, 0.2}.
//
// Round-9: occupancy doubled to the hardware cap. r8 counters showed
// VALUBusy 24-28% + Occupancy 29% + VGPR=64 -> latency-bound with the grid
// (4096 waves) capping residency at 50%. Now: 1024 blocks x 512 threads
// (8 waves), 1 channel/thread -> 8192 waves = 32 waves/CU = 100% residency
// (launch_bounds(512,8) keeps VGPR<=64; live set ~55). Per-wave chain
// halves (5 loads, 20 dot FMAs, 20 phase-C FMAs). All r4 invariants kept:
// 32-n window = full 128-B lines; 8 rows x full line per load/store inst;
// feats held in regs (read exactly once); Gray-code lattice; nt stores.

constexpr int L_VIEWS = 5;
constexpr int C_CH    = 64;
constexpr int NPIX    = 128 * 256;   // 32768

typedef float floatx4 __attribute__((ext_vector_type(4)));

__global__ __launch_bounds__(512, 8)
void shapley_fusion_kernel(const float* __restrict__ feats,
                           const float* __restrict__ w,
                           const float* __restrict__ bptr,
                           float* __restrict__ out)
{
    const int tid  = threadIdx.x;
    const int h    = tid >> 6;         // wave in block (0..7)
    const int lane = tid & 63;
    const int q    = lane & 7;         // n-quad within the 32-n window
    const int g    = lane >> 3;        // channel group within wave (0..7)
    const int win  = blockIdx.x * 32;  // 128-B aligned n window
    const int nq   = win + q * 4;
    const int c    = h * 8 + g;        // this thread's single channel

    const float wc   = w[c];
    const float bias = bptr[0];

    // ---- Phase A: load 5 float4s (one per view; held in regs throughout).
    // Per instruction: q spans 128 B contiguous, g spans 8 rows -> 8 full
    // cache lines, zero partial-line traffic.
    float4 va[L_VIEWS];
#pragma unroll
    for (int l = 0; l < L_VIEWS; ++l)
        va[l] = *reinterpret_cast<const float4*>(
            feats + ((size_t)(l * C_CH + c) * NPIX + nq));

    // Partial dots (this thread's 1 channel), per n sub-index j.
    float d[L_VIEWS][4];
#pragma unroll
    for (int l = 0; l < L_VIEWS; ++l) {
        d[l][0] = va[l].x * wc;
        d[l][1] = va[l].y * wc;
        d[l][2] = va[l].z * wc;
        d[l][3] = va[l].w * wc;
    }

    // Butterfly over the 8 channel-groups (lane bits 3..5).
#pragma unroll
    for (int l = 0; l < L_VIEWS; ++l) {
#pragma unroll
        for (int j = 0; j < 4; ++j) {
            d[l][j] += __shfl_xor(d[l][j], 8, 64);
            d[l][j] += __shfl_xor(d[l][j], 16, 64);
            d[l][j] += __shfl_xor(d[l][j], 32, 64);
        }
    }

    // ---- Cross-wave exchange: 8 waves x 8 quads x 5 views (5 KB LDS). ----
    __shared__ float4 xl[8][8][L_VIEWS];      // [wave][quad][l] = d[l][0..3]
    if (g == 0) {
#pragma unroll
        for (int l = 0; l < L_VIEWS; ++l) {
            float4 t; t.x = d[l][0]; t.y = d[l][1]; t.z = d[l][2]; t.w = d[l][3];
            xl[h][q][l] = t;
        }
    }
    __syncthreads();

    // Each thread finalizes d only for its own j = g&3 (4-way split).
    // LDS addr: q-stride 20 floats -> distinct banks across q; same (q,jm)
    // lanes broadcast.
    const int jm = g & 3;
    const float* xf = reinterpret_cast<const float*>(xl);
    float dm[L_VIEWS];
#pragma unroll
    for (int l = 0; l < L_VIEWS; ++l) {
        float s = 0.f;
#pragma unroll
        for (int hh = 0; hh < 8; ++hh)
            s += xf[(((hh * 8 + q) * L_VIEWS) + l) * 4 + jm];
        dm[l] = s;
    }

    // ---- Phase B: Gray-code subset walk -> shapley -> softmax.
    // Subsets g_t = t ^ (t>>1), t=1..31; step t flips bit ctz(t). One
    // running sum S replaces an s[32] lattice array.
    constexpr float WTS[6] = {0.f, -0.6f, 0.05f, 1.0f / 30.0f, 0.05f, 0.2f};

    float S = bias;
    float sh[L_VIEWS] = {0.f, 0.f, 0.f, 0.f, 0.f};
#pragma unroll
    for (int t = 1; t < 32; ++t) {
        const int gm   = t ^ (t >> 1);           // current subset (compile-time)
        const int bit  = __builtin_ctz(t);        // flipped view index
        const bool add = (gm >> bit) & 1;
        S = add ? (S + dm[bit]) : (S - dm[bit]);
        const float f  = fmaxf(S, 0.f);
        const float wt = WTS[__builtin_popcount(gm)];
#pragma unroll
        for (int i = 0; i < L_VIEWS; ++i)
            if (gm & (1 << i)) sh[i] += wt * f;   // fmac with literal wt
    }

    float mx = sh[0];
#pragma unroll
    for (int i = 1; i < L_VIEWS; ++i) mx = fmaxf(mx, sh[i]);
    float e[L_VIEWS];
    float sum = 0.f;
#pragma unroll
    for (int i = 0; i < L_VIEWS; ++i) { e[i] = __expf(sh[i] - mx); sum += e[i]; }
    const float inv = 1.f / sum;
    float attn_mine[L_VIEWS];
#pragma unroll
    for (int i = 0; i < L_VIEWS; ++i) attn_mine[i] = e[i] * inv;

    // Redistribute: attn[l][j] taken from lane q + 8*j (its jm == j).
    float attn[L_VIEWS][4];
#pragma unroll
    for (int l = 0; l < L_VIEWS; ++l)
#pragma unroll
        for (int j = 0; j < 4; ++j)
            attn[l][j] = __shfl(attn_mine[l], q + 8 * j, 64);

    // ---- Phase C: fused output straight from registers (no re-read).
    floatx4 acc;
    acc.x = va[0].x * attn[0][0];
    acc.y = va[0].y * attn[0][1];
    acc.z = va[0].z * attn[0][2];
    acc.w = va[0].w * attn[0][3];
#pragma unroll
    for (int l = 1; l < L_VIEWS; ++l) {
        acc.x += va[l].x * attn[l][0];
        acc.y += va[l].y * attn[l][1];
        acc.z += va[l].z * attn[l][2];
        acc.w += va[l].w * attn[l][3];
    }
    __builtin_nontemporal_store(acc,
        reinterpret_cast<floatx4*>(out + (size_t)c * NPIX + nq));
}

extern "C" void kernel_launch(void* const* d_in, const int* in_sizes, int n_in,
                              void* d_out, int out_size, void* d_ws, size_t ws_size,
                              hipStream_t stream) {
    const float* feats = (const float*)d_in[0];   // [5,64,128,256] fp32
    const float* w     = (const float*)d_in[1];   // [64,1] fp32
    const float* b     = (const float*)d_in[2];   // [1] fp32
    float* out         = (float*)d_out;           // [64,128,256] fp32

    // 1024 blocks x 512 threads = 8192 waves = 32 waves/CU (hardware cap).
    shapley_fusion_kernel<<<NPIX / 32, 512, 0, stream>>>(feats, w, b, out);
}

// Round 10
// 15.271 us; speedup vs baseline: 3.3299x; 1.3189x over previous
//
#include <hip/hip_runtime.h>

// Shapley fusion: L=5 views, C=64 channels, N=128*256 spatial positions.
// f(subset) = relu(b + sum_{l in subset} d[l]) where d[l] = dot(feats[l,:,n], w)
// -- the reference's [M,N,C] subset GEMM collapses to 5 dots per pixel.
// Shapley coef for L=5 by subset size: {-, -0.6, 0.05, 1/30, 0.05, 0.2}.
//
// Round-10: r7 base (proven 15.6us; r9's 8-wave blocks regressed) plus:
//  (1) 2-deep software pipeline: 512 blocks x 256 thr, two adjacent 32-n
//      windows per block. Loads for BOTH windows issue up front; win1's
//      10 loads stay in flight (vmcnt(10)) under win0's compute -> the
//      cold 40MB stream overlaps the ~5us compute phase that r8 showed
//      was serialized with it (phase-lockstep).
//  (2) DS-pipe diet: xor8 butterfly round via DPP row_ror:8 fused add
//      (VALU, ~25% busy) instead of ds_swizzle (LDS pipe, the hot-pass hog:
//      ~105 DS ops/thread at 16 waves/CU ~= 35% of hot-pass cycles).
// Geometry invariants kept: 32-n window = full 128-B lines; every global
// load/store touches 8 rows x full lines; feats held in regs (read once);
// Gray-code lattice; nontemporal stores.

constexpr int L_VIEWS = 5;
constexpr int C_CH    = 64;
constexpr int NPIX    = 128 * 256;   // 32768

typedef float floatx4 __attribute__((ext_vector_type(4)));

// lane^8 exchange+add within 16-lane DPP rows (row_ror:8 == xor8 there),
// executed on the VALU pipe -- no LDS-pipe traffic.
__device__ __forceinline__ float xor8_add_dpp(float x) {
    int y = __builtin_amdgcn_update_dpp(0, __float_as_int(x),
                                        0x128 /*row_ror:8*/, 0xF, 0xF, true);
    return x + __int_as_float(y);
}

struct Ctx {
    int q, g, h, jm, cA, cB;
    float w0, w1, bias;
};

// Compute + store one 32-n window whose 10 feats float4s are already in va.
__device__ __forceinline__ void window_compute(
    const Ctx& cx, const float4 (&va)[L_VIEWS][2], int nq,
    float4 (*xl)[8][L_VIEWS],              // [wave][quad][l], this window's buffer
    float* __restrict__ out)
{
    // Partial dots over this thread's 2 channels.
    float d[L_VIEWS][4];
#pragma unroll
    for (int l = 0; l < L_VIEWS; ++l) {
        d[l][0] = va[l][0].x * cx.w0 + va[l][1].x * cx.w1;
        d[l][1] = va[l][0].y * cx.w0 + va[l][1].y * cx.w1;
        d[l][2] = va[l][0].z * cx.w0 + va[l][1].z * cx.w1;
        d[l][3] = va[l][0].w * cx.w0 + va[l][1].w * cx.w1;
    }

    // Butterfly over the 8 channel-groups: xor8 on VALU (DPP), rest on DS.
#pragma unroll
    for (int l = 0; l < L_VIEWS; ++l) {
#pragma unroll
        for (int j = 0; j < 4; ++j) {
            d[l][j] = xor8_add_dpp(d[l][j]);
            d[l][j] += __shfl_xor(d[l][j], 16, 64);
            d[l][j] += __shfl_xor(d[l][j], 32, 64);
        }
    }

    // Cross-wave exchange (2.5 KB LDS, one barrier).
    if (cx.g == 0) {
#pragma unroll
        for (int l = 0; l < L_VIEWS; ++l) {
            float4 t; t.x = d[l][0]; t.y = d[l][1]; t.z = d[l][2]; t.w = d[l][3];
            xl[cx.h][cx.q][l] = t;
        }
    }
    __syncthreads();

    // Each thread finalizes d only for its own j = g&3 (phase B split 4-way).
    const float* xf = reinterpret_cast<const float*>(xl);
    float dm[L_VIEWS];
#pragma unroll
    for (int l = 0; l < L_VIEWS; ++l) {
        float s = 0.f;
#pragma unroll
        for (int hh = 0; hh < 4; ++hh)
            s += xf[(((hh * 8 + cx.q) * L_VIEWS) + l) * 4 + cx.jm];
        dm[l] = s;
    }

    // Gray-code subset walk -> shapley weights.
    constexpr float WTS[6] = {0.f, -0.6f, 0.05f, 1.0f / 30.0f, 0.05f, 0.2f};
    float S = cx.bias;
    float sh[L_VIEWS] = {0.f, 0.f, 0.f, 0.f, 0.f};
#pragma unroll
    for (int t = 1; t < 32; ++t) {
        const int gm   = t ^ (t >> 1);
        const int bit  = __builtin_ctz(t);
        const bool add = (gm >> bit) & 1;
        S = add ? (S + dm[bit]) : (S - dm[bit]);
        const float f  = fmaxf(S, 0.f);
        const float wt = WTS[__builtin_popcount(gm)];
#pragma unroll
        for (int i = 0; i < L_VIEWS; ++i)
            if (gm & (1 << i)) sh[i] += wt * f;
    }

    // Softmax over views.
    float mx = sh[0];
#pragma unroll
    for (int i = 1; i < L_VIEWS; ++i) mx = fmaxf(mx, sh[i]);
    float e[L_VIEWS];
    float sum = 0.f;
#pragma unroll
    for (int i = 0; i < L_VIEWS; ++i) { e[i] = __expf(sh[i] - mx); sum += e[i]; }
    const float inv = 1.f / sum;
    float attn_mine[L_VIEWS];
#pragma unroll
    for (int i = 0; i < L_VIEWS; ++i) attn_mine[i] = e[i] * inv;

    // Redistribute: attn[l][j] from lane q + 8*j (that lane owns jm==j).
    float attn[L_VIEWS][4];
#pragma unroll
    for (int l = 0; l < L_VIEWS; ++l)
#pragma unroll
        for (int j = 0; j < 4; ++j)
            attn[l][j] = __shfl(attn_mine[l], cx.q + 8 * j, 64);

    // Fused output straight from registers (no feats re-read).
#pragma unroll
    for (int k = 0; k < 2; ++k) {
        const int c = (k == 0) ? cx.cA : cx.cB;
        floatx4 acc;
        acc.x = va[0][k].x * attn[0][0];
        acc.y = va[0][k].y * attn[0][1];
        acc.z = va[0][k].z * attn[0][2];
        acc.w = va[0][k].w * attn[0][3];
#pragma unroll
        for (int l = 1; l < L_VIEWS; ++l) {
            acc.x += va[l][k].x * attn[l][0];
            acc.y += va[l][k].y * attn[l][1];
            acc.z += va[l][k].z * attn[l][2];
            acc.w += va[l][k].w * attn[l][3];
        }
        __builtin_nontemporal_store(acc,
            reinterpret_cast<floatx4*>(out + (size_t)c * NPIX + nq));
    }
}

__global__ __launch_bounds__(256)
void shapley_fusion_kernel(const float* __restrict__ feats,
                           const float* __restrict__ w,
                           const float* __restrict__ bptr,
                           float* __restrict__ out)
{
    Ctx cx;
    const int tid  = threadIdx.x;
    cx.h    = tid >> 6;                // wave in block (0..3): channel quarter
    const int lane = tid & 63;
    cx.q    = lane & 7;                // n-quad within a 32-n window
    cx.g    = (lane >> 3) & 7;         // channel group within wave
    cx.jm   = cx.g & 3;
    cx.cA   = cx.h * 8 + cx.g;         // this thread's 2 channels
    cx.cB   = cx.cA + 32;
    cx.w0   = w[cx.cA];
    cx.w1   = w[cx.cB];
    cx.bias = bptr[0];

    // Two adjacent 32-n windows per block (2-deep pipeline).
    const int n0 = blockIdx.x * 64 + cx.q * 4;   // window 0
    const int n1 = n0 + 32;                      // window 1

    // Double-buffered exchange LDS (separate buffers -> single barrier each).
    __shared__ float4 xl[2][4][8][L_VIEWS];

    // ---- Issue ALL 20 loads up front: win0 first, then win1. Compute of
    // win0 waits vmcnt(10) (compiler-counted), win1's loads stay in flight.
    float4 va0[L_VIEWS][2], va1[L_VIEWS][2];
#pragma unroll
    for (int l = 0; l < L_VIEWS; ++l) {
        va0[l][0] = *reinterpret_cast<const float4*>(
            feats + ((size_t)(l * C_CH + cx.cA) * NPIX + n0));
        va0[l][1] = *reinterpret_cast<const float4*>(
            feats + ((size_t)(l * C_CH + cx.cB) * NPIX + n0));
    }
#pragma unroll
    for (int l = 0; l < L_VIEWS; ++l) {
        va1[l][0] = *reinterpret_cast<const float4*>(
            feats + ((size_t)(l * C_CH + cx.cA) * NPIX + n1));
        va1[l][1] = *reinterpret_cast<const float4*>(
            feats + ((size_t)(l * C_CH + cx.cB) * NPIX + n1));
    }

    window_compute(cx, va0, n0, xl[0], out);   // win1 loads in flight here
    window_compute(cx, va1, n1, xl[1], out);
}

extern "C" void kernel_launch(void* const* d_in, const int* in_sizes, int n_in,
                              void* d_out, int out_size, void* d_ws, size_t ws_size,
                              hipStream_t stream) {
    const float* feats = (const float*)d_in[0];   // [5,64,128,256] fp32
    const float* w     = (const float*)d_in[1];   // [64,1] fp32
    const float* b     = (const float*)d_in[2];   // [1] fp32
    float* out         = (float*)d_out;           // [64,128,256] fp32

    // 512 blocks x 256 threads; each block owns two adjacent 32-n windows.
    shapley_fusion_kernel<<<NPIX / 64, 256, 0, stream>>>(feats, w, b, out);
}